// Round 4
// baseline (299.127 us; speedup 1.0000x reference)
//
#include <hip/hip_runtime.h>

#define G 4096
#define BSZ 2
#define NIN 8
#define HID 32
#define JSN 8
#define CHUNK 512
#define ITERS 16

typedef __attribute__((ext_vector_type(8))) short short8;
typedef __attribute__((ext_vector_type(4))) float floatx4;
typedef __attribute__((ext_vector_type(4))) short short4v;
typedef unsigned short ushort_t;

__device__ __forceinline__ float elu1(float v) {
    return v > 0.f ? v : (__expf(v) - 1.f);
}
__device__ __forceinline__ ushort_t f2bf(float f) {
    unsigned u = __float_as_uint(f);
    u += 0x7fffu + ((u >> 16) & 1u);
    return (ushort_t)(u >> 16);
}

// h = elu(x@W_infer+b); s_src/s_dst projections; hT bf16 [b][c][g] via LDS transpose.
__global__ __launch_bounds__(256) void k_setup1(
    const float* __restrict__ x, const float* __restrict__ W,
    const float* __restrict__ bias, const float* __restrict__ We,
    float* __restrict__ h0, ushort_t* __restrict__ hTb,
    float* __restrict__ ssrc, float* __restrict__ sdst) {
    __shared__ __align__(16) ushort_t hs[HID][264];
    int tid = threadIdx.x;
    int t = blockIdx.x * 256 + tid;
    int b = t >> 12;                      // uniform per block (16 blocks/batch)
    int g0 = (blockIdx.x & 15) * 256;
    float xin[NIN];
    const float* xp = x + t * NIN;
#pragma unroll
    for (int k = 0; k < NIN; k++) xin[k] = xp[k];
    float ss = 0.f, sd = 0.f;
    float* hp = h0 + (size_t)t * HID;
#pragma unroll
    for (int o = 0; o < HID; o++) {
        float v = bias[o];
#pragma unroll
        for (int k = 0; k < NIN; k++) v += xin[k] * W[k * HID + o];
        v = elu1(v);
        hp[o] = v;
        hs[o][tid] = f2bf(v);
        ss += v * We[o];
        sd += v * We[HID + o];
    }
    ssrc[t] = ss;
    sdst[t] = sd;
    __syncthreads();
#pragma unroll
    for (int p = 0; p < 4; p++) {
        int row = p * 8 + (tid >> 5);
        int c = (tid & 31) * 8;
        short8 v8 = *(const short8*)&hs[row][c];
        *(short8*)(void*)&hTb[(size_t)(b * HID + row) * G + g0 + c] = v8;
    }
}

// MFMA aggregation, depth-4 register prefetch, ssrc staged in LDS.
// Wave w: b=w>>1, ihalf=w&1. A-frag e: lane l = (m=l&15, k=(l>>4)*8+t).
__global__ __launch_bounds__(256, 4) void k_main(
    const float* __restrict__ adj, const float* __restrict__ ssrc,
    const float* __restrict__ sdst, const ushort_t* __restrict__ hTb,
    const float* __restrict__ bep, float coef, float* __restrict__ part) {
    __shared__ __align__(16) float ssm[BSZ][CHUNK];
    int tid = threadIdx.x;
    int w = tid >> 6, l = tid & 63;
    int b = w >> 1, ihalf = w & 1;
    int i0 = blockIdx.x * 32;
    int jbase = blockIdx.y * CHUNK;
    // stage ssrc chunk: 2*512 floats by 256 threads (float4 each)
    {
        int bb = tid >> 7, ix = (tid & 127) * 4;
        *(float4*)&ssm[bb][ix] = *(const float4*)&ssrc[bb * G + jbase + ix];
    }
    int i = i0 + ihalf * 16 + (l & 15);
    int kg = l >> 4;
    float sd = sdst[b * G + i] + bep[0];
    float wm1 = 1.f - coef;
    const float* adjrow = adj + (size_t)i * G + jbase + kg * 8;
    const ushort_t* hb0 = hTb + (size_t)(b * HID + (l & 15)) * G + jbase + kg * 8;
    const ushort_t* hb1 = hb0 + (size_t)16 * G;
    floatx4 c0 = {0.f, 0.f, 0.f, 0.f}, c1 = {0.f, 0.f, 0.f, 0.f};
    float es = 0.f;

    float4 pa0[4], pa1[4];
    short8 pb0[4], pb1[4];
#pragma unroll
    for (int d = 0; d < 4; d++) {
        pa0[d] = *(const float4*)(adjrow + d * 32);
        pa1[d] = *(const float4*)(adjrow + d * 32 + 4);
        pb0[d] = *(const short8*)(const void*)(hb0 + d * 32);
        pb1[d] = *(const short8*)(const void*)(hb1 + d * 32);
    }
    __syncthreads();
    const float* svp = &ssm[b][kg * 8];

    for (int jc = 0; jc < ITERS; jc += 4) {
#pragma unroll
        for (int d = 0; d < 4; d++) {
            float4 a0 = pa0[d], a1 = pa1[d];
            short8 bf0 = pb0[d], bf1 = pb1[d];
            int nj = jc + 4 + d;
            if (nj < ITERS) {
                pa0[d] = *(const float4*)(adjrow + nj * 32);
                pa1[d] = *(const float4*)(adjrow + nj * 32 + 4);
                pb0[d] = *(const short8*)(const void*)(hb0 + nj * 32);
                pb1[d] = *(const short8*)(const void*)(hb1 + nj * 32);
            }
            float4 s0 = *(const float4*)&svp[(jc + d) * 32];
            float4 s1 = *(const float4*)&svp[(jc + d) * 32 + 4];
            float av[8] = {a0.x, a0.y, a0.z, a0.w, a1.x, a1.y, a1.z, a1.w};
            float sv[8] = {s0.x, s0.y, s0.z, s0.w, s1.x, s1.y, s1.z, s1.w};
            short8 af;
#pragma unroll
            for (int t = 0; t < 8; t++) {
                float wgt = __builtin_fmaf(av[t], wm1, coef);  // exact for adj in {0,1}
                float sg = __builtin_amdgcn_rcpf(1.f + __expf(-(sd + sv[t])));
                float e = sg * wgt;
                es += e;
                af[t] = (short)f2bf(e);
            }
            c0 = __builtin_amdgcn_mfma_f32_16x16x32_bf16(af, bf0, c0, 0, 0, 0);
            c1 = __builtin_amdgcn_mfma_f32_16x16x32_bf16(af, bf1, c1, 0, 0, 0);
        }
    }
    es += __shfl_xor(es, 16);
    es += __shfl_xor(es, 32);
    int jsb = blockIdx.y;
#pragma unroll
    for (int r = 0; r < 4; r++) {
        int row = i0 + ihalf * 16 + kg * 4 + r;  // C/D: row=(l>>4)*4+reg, col=l&15
        size_t base = ((size_t)(b * G + row) * JSN + jsb) * 36;
        part[base + (l & 15)] = c0[r];
        part[base + 16 + (l & 15)] = c1[r];
    }
    if (l < 16) part[((size_t)(b * G + i) * JSN + jsb) * 36 + 32] = es;
}

// Reduce partials; node+merge MLPs; optional fused BN + We2 proj + hT write.
// 4 genes (8 rows) per block; wave = 2 rows = one gene's (b=0,b=1).
template <bool DO_BN>
__global__ __launch_bounds__(256) void k_post(
    const float* __restrict__ part, const float* __restrict__ hin,
    const float* __restrict__ Wn, const float* __restrict__ bnb,
    const float* __restrict__ Wm, const float* __restrict__ bmb,
    const float* __restrict__ gamma, const float* __restrict__ beta,
    const float* __restrict__ We2, float* __restrict__ outp,
    ushort_t* __restrict__ hTb, float* __restrict__ s2s,
    float* __restrict__ s2d) {
    __shared__ float Wns[64 * 32];
    __shared__ float Wms[64 * 32];
    __shared__ float rec[8][68];
    __shared__ float rec2[8][68];
    __shared__ ushort_t tb[BSZ][HID][4];
    int tid = threadIdx.x;
    int rl = tid >> 5, hh = tid & 31;
#pragma unroll
    for (int r = 0; r < 8; r++) {
        Wns[r * 256 + tid] = Wn[r * 256 + tid];
        Wms[r * 256 + tid] = Wm[r * 256 + tid];
    }
    int g0 = blockIdx.x * 4;
    int b = rl & 1;
    int g = g0 + (rl >> 1);
    int rowf = b * G + g;
    float rs = 0.f, es = 0.f;
    size_t rbase = (size_t)rowf * JSN * 36;
#pragma unroll
    for (int js = 0; js < JSN; js++) {
        rs += part[rbase + js * 36 + hh];
        es += part[rbase + js * 36 + 32];
    }
    float xv = hin[(size_t)rowf * HID + hh];
    rec[rl][hh] = rs;
    rec[rl][32 + hh] = xv * es;
    __syncthreads();
    float v = bnb[hh];
#pragma unroll
    for (int k4 = 0; k4 < 16; k4++) {
        float4 r4 = *(const float4*)&rec[rl][k4 * 4];
        v += r4.x * Wns[(k4 * 4 + 0) * HID + hh];
        v += r4.y * Wns[(k4 * 4 + 1) * HID + hh];
        v += r4.z * Wns[(k4 * 4 + 2) * HID + hh];
        v += r4.w * Wns[(k4 * 4 + 3) * HID + hh];
    }
    v = elu1(v);
    rec2[rl][hh] = v;
    rec2[rl][32 + hh] = xv;
    __syncthreads();
    float u = bmb[hh];
#pragma unroll
    for (int k4 = 0; k4 < 16; k4++) {
        float4 r4 = *(const float4*)&rec2[rl][k4 * 4];
        u += r4.x * Wms[(k4 * 4 + 0) * HID + hh];
        u += r4.y * Wms[(k4 * 4 + 1) * HID + hh];
        u += r4.z * Wms[(k4 * 4 + 2) * HID + hh];
        u += r4.w * Wms[(k4 * 4 + 3) * HID + hh];
    }
    float h1v = elu1(u);
    if (!DO_BN) {
        outp[(size_t)rowf * HID + hh] = h1v;
    } else {
        // wave = gene g's 64 values (b = lane>>5, feature = lane&31)
        float s = h1v, sq = h1v * h1v;
#pragma unroll
        for (int m = 32; m; m >>= 1) {
            s += __shfl_xor(s, m);
            sq += __shfl_xor(sq, m);
        }
        float mu = s * (1.f / 64.f);
        float var = sq * (1.f / 64.f) - mu * mu;
        float rstd = rsqrtf(var + 1e-5f);
        float hn = (h1v - mu) * rstd * gamma[g] + beta[g];
        outp[(size_t)rowf * HID + hh] = hn;
        tb[b][hh][rl >> 1] = f2bf(hn);
        float ps = hn * We2[hh], pd = hn * We2[HID + hh];
#pragma unroll
        for (int m = 16; m; m >>= 1) {
            ps += __shfl_xor(ps, m);
            pd += __shfl_xor(pd, m);
        }
        if (hh == 0) {
            s2s[rowf] = ps;
            s2d[rowf] = pd;
        }
        __syncthreads();
        if (tid < 64) {
            int b2 = tid >> 5, c = tid & 31;
            short4v val = *(const short4v*)&tb[b2][c][0];
            *(short4v*)(void*)&hTb[(size_t)(b2 * HID + c) * G + g0] = val;
        }
    }
}

extern "C" void kernel_launch(void* const* d_in, const int* in_sizes, int n_in,
                              void* d_out, int out_size, void* d_ws, size_t ws_size,
                              hipStream_t stream) {
    const float* x      = (const float*)d_in[0];
    const float* edges1 = (const float*)d_in[1];
    const float* edges2 = (const float*)d_in[2];
    const float* W_inf  = (const float*)d_in[3];
    const float* b_inf  = (const float*)d_in[4];
    const float* W_e1   = (const float*)d_in[5];
    const float* b_e1   = (const float*)d_in[6];
    const float* W_e2   = (const float*)d_in[7];
    const float* b_e2   = (const float*)d_in[8];
    const float* W_n1   = (const float*)d_in[9];
    const float* b_n1   = (const float*)d_in[10];
    const float* W_n2   = (const float*)d_in[11];
    const float* b_n2   = (const float*)d_in[12];
    const float* W_m1   = (const float*)d_in[13];
    const float* b_m1   = (const float*)d_in[14];
    const float* W_m2   = (const float*)d_in[15];
    const float* b_m2   = (const float*)d_in[16];
    const float* bn_g   = (const float*)d_in[17];
    const float* bn_b   = (const float*)d_in[18];
    float* out = (float*)d_out;

    float* ws = (float*)d_ws;
    float* h0   = ws;                        // 262144
    float* h1n  = ws + 262144;               // 262144
    float* s1s  = ws + 524288;               // 8192
    float* s1d  = ws + 532480;               // 8192
    float* s2s  = ws + 540672;               // 8192
    float* s2d  = ws + 548864;               // 8192
    float* part = ws + 557056;               // 2*4096*8*36 = 2359296 floats
    ushort_t* hTb = (ushort_t*)(part + (size_t)BSZ * G * JSN * 36);

    const float ALPHA = 0.005f, BETA = 5e-5f;

    k_setup1<<<32, 256, 0, stream>>>(x, W_inf, b_inf, W_e1, h0, hTb, s1s, s1d);
    k_main<<<dim3(G / 32, JSN), 256, 0, stream>>>(edges1, s1s, s1d, hTb, b_e1, ALPHA, part);
    k_post<true><<<G / 4, 256, 0, stream>>>(part, h0, W_n1, b_n1, W_m1, b_m1,
                                            bn_g, bn_b, W_e2, h1n, hTb, s2s, s2d);
    k_main<<<dim3(G / 32, JSN), 256, 0, stream>>>(edges2, s2s, s2d, hTb, b_e2, BETA, part);
    k_post<false><<<G / 4, 256, 0, stream>>>(part, h1n, W_n2, b_n2, W_m2, b_m2,
                                             nullptr, nullptr, nullptr, out,
                                             nullptr, nullptr, nullptr);
}

// Round 5
// 240.757 us; speedup vs baseline: 1.2424x; 1.2424x over previous
//
#include <hip/hip_runtime.h>

#define G 4096
#define BSZ 2
#define NIN 8
#define HID 32
#define JSN 8
#define CHUNK 512

typedef __attribute__((ext_vector_type(8))) short short8;
typedef __attribute__((ext_vector_type(4))) float floatx4;
typedef __attribute__((ext_vector_type(4))) short short4v;
typedef unsigned short ushort_t;

__device__ __forceinline__ float elu1(float v) {
    return v > 0.f ? v : (__expf(v) - 1.f);
}
__device__ __forceinline__ ushort_t f2bf(float f) {
    unsigned u = __float_as_uint(f);
    u += 0x7fffu + ((u >> 16) & 1u);
    return (ushort_t)(u >> 16);
}

// h = elu(x@W_infer+b); s_src/s_dst projections; hT bf16 [b][c][g] via LDS transpose.
__global__ __launch_bounds__(256) void k_setup1(
    const float* __restrict__ x, const float* __restrict__ W,
    const float* __restrict__ bias, const float* __restrict__ We,
    float* __restrict__ h0, ushort_t* __restrict__ hTb,
    float* __restrict__ ssrc, float* __restrict__ sdst) {
    __shared__ __align__(16) ushort_t hs[HID][264];
    int tid = threadIdx.x;
    int t = blockIdx.x * 256 + tid;
    int b = t >> 12;                      // uniform per block (16 blocks/batch)
    int g0 = (blockIdx.x & 15) * 256;
    float xin[NIN];
    const float* xp = x + t * NIN;
#pragma unroll
    for (int k = 0; k < NIN; k++) xin[k] = xp[k];
    float ss = 0.f, sd = 0.f;
    float* hp = h0 + (size_t)t * HID;
#pragma unroll
    for (int o = 0; o < HID; o++) {
        float v = bias[o];
#pragma unroll
        for (int k = 0; k < NIN; k++) v += xin[k] * W[k * HID + o];
        v = elu1(v);
        hp[o] = v;
        hs[o][tid] = f2bf(v);
        ss += v * We[o];
        sd += v * We[HID + o];
    }
    ssrc[t] = ss;
    sdst[t] = sd;
    __syncthreads();
#pragma unroll
    for (int p = 0; p < 4; p++) {
        int row = p * 8 + (tid >> 5);
        int c = (tid & 31) * 8;
        short8 v8 = *(const short8*)&hs[row][c];
        *(short8*)(void*)&hTb[(size_t)(b * HID + row) * G + g0 + c] = v8;
    }
}

// MFMA aggregation. 512-thr block = 8 waves (b, ihalf, jhalf); each wave does
// 256 j (8 iters, depth-2 prefetch); jhalf pairs merge via LDS; dense aligned
// part writes (one 128-B line per row, single-writer).
// A-frag e: lane l = (m=l&15, k=(l>>4)*8+t).
__global__ __launch_bounds__(512, 8) void k_main(
    const float* __restrict__ adj, const float* __restrict__ ssrc,
    const float* __restrict__ sdst, const ushort_t* __restrict__ hTb,
    const float* __restrict__ bep, float coef,
    float* __restrict__ part_recv, float* __restrict__ part_es) {
    __shared__ __align__(16) float ssm[BSZ][CHUNK];
    __shared__ float red[4][64][9];
    int tid = threadIdx.x;
    int w = tid >> 6, l = tid & 63;
    int b = w >> 2, ihalf = (w >> 1) & 1, jh = w & 1;
    int i0 = blockIdx.x * 32;
    int jbase = blockIdx.y * CHUNK;
    if (tid < 256) {
        int bb = tid >> 7, ix = (tid & 127) * 4;
        *(float4*)&ssm[bb][ix] = *(const float4*)&ssrc[bb * G + jbase + ix];
    }
    int m = l & 15, kg = l >> 4;
    int i = i0 + ihalf * 16 + m;
    float sd = sdst[b * G + i] + bep[0];
    float wm1 = 1.f - coef;
    int joff = jbase + jh * 256 + kg * 8;
    const float* adjrow = adj + (size_t)i * G + joff;
    const ushort_t* hb0 = hTb + (size_t)(b * HID + m) * G + joff;
    const ushort_t* hb1 = hb0 + (size_t)16 * G;
    floatx4 c0 = {0.f, 0.f, 0.f, 0.f}, c1 = {0.f, 0.f, 0.f, 0.f};
    float es = 0.f;

    float4 pa0[2], pa1[2];
    short8 pb0[2], pb1[2];
#pragma unroll
    for (int d = 0; d < 2; d++) {
        pa0[d] = *(const float4*)(adjrow + d * 32);
        pa1[d] = *(const float4*)(adjrow + d * 32 + 4);
        pb0[d] = *(const short8*)(const void*)(hb0 + d * 32);
        pb1[d] = *(const short8*)(const void*)(hb1 + d * 32);
    }
    __syncthreads();
    const float* svp = &ssm[b][jh * 256 + kg * 8];

#pragma unroll
    for (int jc = 0; jc < 8; jc++) {
        int cur = jc & 1;
        float4 a0 = pa0[cur], a1 = pa1[cur];
        short8 bf0 = pb0[cur], bf1 = pb1[cur];
        if (jc + 2 < 8) {
            int o = (jc + 2) * 32;
            pa0[cur] = *(const float4*)(adjrow + o);
            pa1[cur] = *(const float4*)(adjrow + o + 4);
            pb0[cur] = *(const short8*)(const void*)(hb0 + o);
            pb1[cur] = *(const short8*)(const void*)(hb1 + o);
        }
        float4 s0 = *(const float4*)&svp[jc * 32];
        float4 s1 = *(const float4*)&svp[jc * 32 + 4];
        float av[8] = {a0.x, a0.y, a0.z, a0.w, a1.x, a1.y, a1.z, a1.w};
        float sv[8] = {s0.x, s0.y, s0.z, s0.w, s1.x, s1.y, s1.z, s1.w};
        short8 af;
#pragma unroll
        for (int t = 0; t < 8; t++) {
            float wgt = __builtin_fmaf(av[t], wm1, coef);  // exact for adj in {0,1}
            float sg = __builtin_amdgcn_rcpf(1.f + __expf(-(sd + sv[t])));
            float e = sg * wgt;
            es += e;
            af[t] = (short)f2bf(e);
        }
        c0 = __builtin_amdgcn_mfma_f32_16x16x32_bf16(af, bf0, c0, 0, 0, 0);
        c1 = __builtin_amdgcn_mfma_f32_16x16x32_bf16(af, bf1, c1, 0, 0, 0);
    }
    // merge jhalf pairs through LDS
    int slot = w >> 1;
    if (jh) {
#pragma unroll
        for (int r = 0; r < 4; r++) {
            red[slot][l][r] = c0[r];
            red[slot][l][4 + r] = c1[r];
        }
        red[slot][l][8] = es;
    }
    __syncthreads();
    if (!jh) {
#pragma unroll
        for (int r = 0; r < 4; r++) {
            c0[r] += red[slot][l][r];
            c1[r] += red[slot][l][4 + r];
        }
        es += red[slot][l][8];
        es += __shfl_xor(es, 16);
        es += __shfl_xor(es, 32);
        size_t rb = ((size_t)(blockIdx.y * BSZ + b)) * G;
#pragma unroll
        for (int r = 0; r < 4; r++) {
            int row = i0 + ihalf * 16 + kg * 4 + r;  // C/D: row=(l>>4)*4+reg, col=l&15
            part_recv[(rb + row) * 32 + m] = c0[r];
            part_recv[(rb + row) * 32 + 16 + m] = c1[r];
        }
        if (l < 16) part_es[rb + i] = es;
    }
}

// Reduce partials; node+merge MLPs; optional fused BN + We2 proj + hT write.
// 4 genes (8 rows) per block; wave = 2 rows = one gene's (b=0,b=1).
template <bool DO_BN>
__global__ __launch_bounds__(256) void k_post(
    const float* __restrict__ part_recv, const float* __restrict__ part_es,
    const float* __restrict__ hin,
    const float* __restrict__ Wn, const float* __restrict__ bnb,
    const float* __restrict__ Wm, const float* __restrict__ bmb,
    const float* __restrict__ gamma, const float* __restrict__ beta,
    const float* __restrict__ We2, float* __restrict__ outp,
    ushort_t* __restrict__ hTb, float* __restrict__ s2s,
    float* __restrict__ s2d) {
    __shared__ float Wns[64 * 32];
    __shared__ float Wms[64 * 32];
    __shared__ float rec[8][68];
    __shared__ float rec2[8][68];
    __shared__ ushort_t tb[BSZ][HID][4];
    int tid = threadIdx.x;
    int rl = tid >> 5, hh = tid & 31;
#pragma unroll
    for (int r = 0; r < 8; r++) {
        Wns[r * 256 + tid] = Wn[r * 256 + tid];
        Wms[r * 256 + tid] = Wm[r * 256 + tid];
    }
    int g0 = blockIdx.x * 4;
    int b = rl & 1;
    int g = g0 + (rl >> 1);
    int rowf = b * G + g;
    float rs = 0.f, es = 0.f;
#pragma unroll
    for (int js = 0; js < JSN; js++) {
        size_t sb = (size_t)(js * BSZ + b) * G + g;
        rs += part_recv[sb * 32 + hh];
        es += part_es[sb];
    }
    float xv = hin[(size_t)rowf * HID + hh];
    rec[rl][hh] = rs;
    rec[rl][32 + hh] = xv * es;
    __syncthreads();
    float v = bnb[hh];
#pragma unroll
    for (int k4 = 0; k4 < 16; k4++) {
        float4 r4 = *(const float4*)&rec[rl][k4 * 4];
        v += r4.x * Wns[(k4 * 4 + 0) * HID + hh];
        v += r4.y * Wns[(k4 * 4 + 1) * HID + hh];
        v += r4.z * Wns[(k4 * 4 + 2) * HID + hh];
        v += r4.w * Wns[(k4 * 4 + 3) * HID + hh];
    }
    v = elu1(v);
    rec2[rl][hh] = v;
    rec2[rl][32 + hh] = xv;
    __syncthreads();
    float u = bmb[hh];
#pragma unroll
    for (int k4 = 0; k4 < 16; k4++) {
        float4 r4 = *(const float4*)&rec2[rl][k4 * 4];
        u += r4.x * Wms[(k4 * 4 + 0) * HID + hh];
        u += r4.y * Wms[(k4 * 4 + 1) * HID + hh];
        u += r4.z * Wms[(k4 * 4 + 2) * HID + hh];
        u += r4.w * Wms[(k4 * 4 + 3) * HID + hh];
    }
    float h1v = elu1(u);
    if (!DO_BN) {
        outp[(size_t)rowf * HID + hh] = h1v;
    } else {
        // wave = gene g's 64 values (b = lane>>5, feature = lane&31)
        float s = h1v, sq = h1v * h1v;
#pragma unroll
        for (int mm = 32; mm; mm >>= 1) {
            s += __shfl_xor(s, mm);
            sq += __shfl_xor(sq, mm);
        }
        float mu = s * (1.f / 64.f);
        float var = sq * (1.f / 64.f) - mu * mu;
        float rstd = rsqrtf(var + 1e-5f);
        float hn = (h1v - mu) * rstd * gamma[g] + beta[g];
        outp[(size_t)rowf * HID + hh] = hn;
        tb[b][hh][rl >> 1] = f2bf(hn);
        float ps = hn * We2[hh], pd = hn * We2[HID + hh];
#pragma unroll
        for (int mm = 16; mm; mm >>= 1) {
            ps += __shfl_xor(ps, mm);
            pd += __shfl_xor(pd, mm);
        }
        if (hh == 0) {
            s2s[rowf] = ps;
            s2d[rowf] = pd;
        }
        __syncthreads();
        if (tid < 64) {
            int b2 = tid >> 5, c = tid & 31;
            short4v val = *(const short4v*)&tb[b2][c][0];
            *(short4v*)(void*)&hTb[(size_t)(b2 * HID + c) * G + g0] = val;
        }
    }
}

extern "C" void kernel_launch(void* const* d_in, const int* in_sizes, int n_in,
                              void* d_out, int out_size, void* d_ws, size_t ws_size,
                              hipStream_t stream) {
    const float* x      = (const float*)d_in[0];
    const float* edges1 = (const float*)d_in[1];
    const float* edges2 = (const float*)d_in[2];
    const float* W_inf  = (const float*)d_in[3];
    const float* b_inf  = (const float*)d_in[4];
    const float* W_e1   = (const float*)d_in[5];
    const float* b_e1   = (const float*)d_in[6];
    const float* W_e2   = (const float*)d_in[7];
    const float* b_e2   = (const float*)d_in[8];
    const float* W_n1   = (const float*)d_in[9];
    const float* b_n1   = (const float*)d_in[10];
    const float* W_n2   = (const float*)d_in[11];
    const float* b_n2   = (const float*)d_in[12];
    const float* W_m1   = (const float*)d_in[13];
    const float* b_m1   = (const float*)d_in[14];
    const float* W_m2   = (const float*)d_in[15];
    const float* b_m2   = (const float*)d_in[16];
    const float* bn_g   = (const float*)d_in[17];
    const float* bn_b   = (const float*)d_in[18];
    float* out = (float*)d_out;

    float* ws = (float*)d_ws;
    float* h0   = ws;                        // 262144
    float* h1n  = ws + 262144;               // 262144
    float* s1s  = ws + 524288;               // 8192
    float* s1d  = ws + 532480;               // 8192
    float* s2s  = ws + 540672;               // 8192
    float* s2d  = ws + 548864;               // 8192
    float* part_recv = ws + 557056;          // 8*2*4096*32 = 2097152
    float* part_es   = ws + 2654208;         // 8*2*4096   = 65536
    ushort_t* hTb = (ushort_t*)(ws + 2719744);  // 262144 bf16

    const float ALPHA = 0.005f, BETA = 5e-5f;

    k_setup1<<<32, 256, 0, stream>>>(x, W_inf, b_inf, W_e1, h0, hTb, s1s, s1d);
    k_main<<<dim3(G / 32, JSN), 512, 0, stream>>>(edges1, s1s, s1d, hTb, b_e1, ALPHA,
                                                  part_recv, part_es);
    k_post<true><<<G / 4, 256, 0, stream>>>(part_recv, part_es, h0, W_n1, b_n1,
                                            W_m1, b_m1, bn_g, bn_b, W_e2, h1n,
                                            hTb, s2s, s2d);
    k_main<<<dim3(G / 32, JSN), 512, 0, stream>>>(edges2, s2s, s2d, hTb, b_e2, BETA,
                                                  part_recv, part_es);
    k_post<false><<<G / 4, 256, 0, stream>>>(part_recv, part_es, h1n, W_n2, b_n2,
                                             W_m2, b_m2, nullptr, nullptr, nullptr,
                                             out, nullptr, nullptr, nullptr);
}